// Round 11
// baseline (282.013 us; speedup 1.0000x reference)
//
#include <hip/hip_runtime.h>

typedef __attribute__((ext_vector_type(4))) float f32x4;
typedef __attribute__((ext_vector_type(8))) unsigned short u16x8;
typedef __attribute__((ext_vector_type(8))) __bf16 bf16x8;

typedef __attribute__((address_space(3))) unsigned lds_u32;
typedef const __attribute__((address_space(1))) unsigned glb_u32;

__device__ __forceinline__ unsigned short f2bf(float f) {
    union { float f; unsigned u; } v; v.f = f;
    unsigned r = v.u + 0x7fffu + ((v.u >> 16) & 1u);
    return (unsigned short)(r >> 16);
}

__device__ __forceinline__ f32x4 mfma16(u16x8 a, u16x8 b, f32x4 c) {
    return __builtin_amdgcn_mfma_f32_16x16x32_bf16(
        __builtin_bit_cast(bf16x8, a), __builtin_bit_cast(bf16x8, b), c, 0, 0, 0);
}

__device__ __forceinline__ void gload16(const unsigned short* g, unsigned short* l) {
    __builtin_amdgcn_global_load_lds((glb_u32*)g, (lds_u32*)l, 16, 0, 0);
}

#define BARM() asm volatile("s_barrier" ::: "memory")
#define WAITVM0() asm volatile("s_waitcnt vmcnt(0)" ::: "memory")

// ---------------- fp32 -> bf16 conversions ----------------
__global__ void cvt_f32_bf16(const float* __restrict__ src,
                             unsigned short* __restrict__ dst, int n) {
    int stride = gridDim.x * blockDim.x * 4;
    for (int i = (blockIdx.x * blockDim.x + threadIdx.x) * 4; i < n; i += stride) {
        float4 f = *reinterpret_cast<const float4*>(src + i);
        ushort4 o;
        o.x = f2bf(f.x); o.y = f2bf(f.y); o.z = f2bf(f.z); o.w = f2bf(f.w);
        *reinterpret_cast<ushort4*>(dst + i) = o;
    }
}

__global__ void cvt4_f32_bf16(const float* __restrict__ s0, const float* __restrict__ s1,
                              const float* __restrict__ s2, const float* __restrict__ s3,
                              unsigned short* __restrict__ dst, int per) {
    int total = per * 4;
    int stride = gridDim.x * blockDim.x * 4;
    for (int i = (blockIdx.x * blockDim.x + threadIdx.x) * 4; i < total; i += stride) {
        int w = i / per, off = i - w * per;
        const float* s = w == 0 ? s0 : w == 1 ? s1 : w == 2 ? s2 : s3;
        float4 f = *reinterpret_cast<const float4*>(s + off);
        ushort4 o;
        o.x = f2bf(f.x); o.y = f2bf(f.y); o.z = f2bf(f.z); o.w = f2bf(f.w);
        *reinterpret_cast<ushort4*>(dst + i) = o;
    }
}

// ---------- 128x128 / BK=64 / single-buffer / 5-blocks-per-CU GEMM ----------
// C = A * B^T + bias. A: M x K bf16 row-major. B: N x K bf16 row-major. K%64==0.
// 256 threads = 4 waves (2x2, 64x64 per wave). LDS 32 KB (A 16K + B 16K,
// SINGLE buffer) -> 5 blocks/CU (5 x 32768 = 160 KiB exactly), 20 waves/CU.
// The per-iter vmcnt(0) drain is covered by the other 4 resident blocks
// (m114 cross-block overlap). Swizzle (proven R8/R10): logical 16B-slot cb of
// row r lives at cb ^ ((r&7)<<4); staged via pre-swizzled source col
// cel = ((t&7)^((t>>3)&7))*8 (involution; reads conflict-free).
// Sync (m97): STAGE(kt); vmcnt(0); barrier; reads+MFMA; barrier.
template<bool OUTF32>
__device__ __forceinline__ void gemm_core(
    const unsigned short* __restrict__ A,
    const unsigned short* __restrict__ B,
    const float* __restrict__ b0, const float* __restrict__ b1, const float* __restrict__ b2,
    void* __restrict__ C0, void* __restrict__ C1, void* __restrict__ C2,
    int K, int NBY)
{
    __shared__ char lds[32768];
    const int t = threadIdx.x, lane = t & 63, wave = t >> 6;
    const int wm = wave >> 1, wn = wave & 1;     // 2x2 wave grid, 64x64 each

    // XCD-aware bijective swizzle (nwg % 8 == 0 by launch)
    const int nwg = gridDim.x;
    const int bid = blockIdx.x;
    const int swzb = (bid & 7) * (nwg >> 3) + (bid >> 3);
    const long m0 = (long)(swzb / NBY) * 128;
    const long n0 = (long)(swzb % NBY) * 128;

    const int NT = K >> 6;                       // K-tiles of 64

    const int rloc = t >> 3;                                 // 0..31
    const int cel  = ((t & 7) ^ ((t >> 3) & 7)) << 3;        // src col element
    const unsigned short* Ab = A + (m0 + rloc) * (long)K + cel;
    const unsigned short* Bb = B + (n0 + rloc) * (long)K + cel;

    auto STAGE = [&](int kt) {
        char* da = lds + (wave << 10);
        char* db = lds + 16384 + (wave << 10);
        const unsigned short* sa = Ab + kt * 64;
        const unsigned short* sb = Bb + kt * 64;
        #pragma unroll
        for (int j = 0; j < 4; ++j) {
            gload16(sa + (long)(j * 32) * K, (unsigned short*)(da + j * 4096));
            gload16(sb + (long)(j * 32) * K, (unsigned short*)(db + j * 4096));
        }
    };

    f32x4 acc[4][4] = {};
    u16x8 af[4][2], bfr[4][2];

    auto LD = [&]() {
        const char* bufA = lds;
        const char* bufB = lds + 16384;
        #pragma unroll
        for (int f = 0; f < 4; ++f)
            #pragma unroll
            for (int kk = 0; kk < 2; ++kk) {
                int ra = wm * 64 + f * 16 + (lane & 15);
                int rb = wn * 64 + f * 16 + (lane & 15);
                int cb = kk * 64 + (lane >> 4) * 16;
                af[f][kk]  = *(const u16x8*)(bufA + ra * 128 + (cb ^ ((ra & 7) << 4)));
                bfr[f][kk] = *(const u16x8*)(bufB + rb * 128 + (cb ^ ((rb & 7) << 4)));
            }
    };

    for (int kt = 0; kt < NT; ++kt) {
        STAGE(kt);
        WAITVM0();
        BARM();                       // buffer ready for all waves
        LD();                         // 16 x ds_read_b128
        #pragma unroll
        for (int kk = 0; kk < 2; ++kk)
            #pragma unroll
            for (int mi = 0; mi < 4; ++mi)
                #pragma unroll
                for (int nf = 0; nf < 4; ++nf)
                    acc[mi][nf] = mfma16(af[mi][kk], bfr[nf][kk], acc[mi][nf]);
        BARM();                       // all reads done -> next STAGE safe
    }

    // ---- epilogue: C/D layout col=lane&15, row=(lane>>4)*4+reg ----
    #pragma unroll
    for (int mi = 0; mi < 4; ++mi)
        #pragma unroll
        for (int nf = 0; nf < 4; ++nf) {
            int coln = (int)n0 + wn * 64 + nf * 16 + (lane & 15);
            int which = coln / 768;
            int nl = coln - which * 768;
            const float* bs = which == 0 ? b0 : (which == 1 ? b1 : b2);
            void* Cp       = which == 0 ? C0 : (which == 1 ? C1 : C2);
            float bias = bs[nl];
            #pragma unroll
            for (int q = 0; q < 4; ++q) {
                long row = m0 + wm * 64 + mi * 16 + ((lane >> 4) << 2) + q;
                float val = acc[mi][nf][q] + bias;
                if (OUTF32) ((float*)Cp)[row * 768 + nl] = val;
                else ((unsigned short*)Cp)[row * 768 + nl] = f2bf(val);
            }
        }
}

__global__ __launch_bounds__(256, 5) void qkv_gemm(
    const unsigned short* __restrict__ A, const unsigned short* __restrict__ B,
    const float* b0, const float* b1, const float* b2,
    void* C0, void* C1, void* C2, int K, int NBY)
{
    gemm_core<false>(A, B, b0, b1, b2, C0, C1, C2, K, NBY);
}

__global__ __launch_bounds__(256, 5) void oproj_gemm(
    const unsigned short* __restrict__ A, const unsigned short* __restrict__ B,
    const float* b0, const float* b1, const float* b2,
    void* C0, void* C1, void* C2, int K, int NBY)
{
    gemm_core<true>(A, B, b0, b1, b2, C0, C1, C2, K, NBY);
}

// ---------------- axial attention, seq len 128, head_dim 64 ----------------
// V is loaded to registers during staging; its (bank-conflicted) transpose
// scatter into Vst is deferred into the QK^T phase so the ds_write traffic
// overlaps the MFMA pipe instead of sitting serially before the first barrier.
__global__ __launch_bounds__(256, 3) void attn128(
    const unsigned short* __restrict__ Q,
    const unsigned short* __restrict__ K,
    const unsigned short* __restrict__ V,
    unsigned short* __restrict__ O,
    int mult, int stride)
{
    __shared__ unsigned short QK[2][128][72];
    __shared__ unsigned short Vst[64][136];
    unsigned short (*Qs)[72] = QK[0];
    unsigned short (*Ks)[72] = QK[1];
    unsigned short (*Ps)[136] = (unsigned short (*)[136])&QK[0][0][0];

    const int pos = blockIdx.x, head = blockIdx.y;
    const int t = threadIdx.x, wave = t >> 6, lane = t & 63;

    // ---- stage Q,K to LDS; V only to registers ----
    u16x8 vv[4];
    #pragma unroll
    for (int p = 0; p < 4; ++p) {
        int f = p * 2048 + t * 8;
        int r = f >> 6;
        int d = f & 63;
        long g = ((long)(pos * mult + r * stride)) * 768 + head * 64 + d;
        *(u16x8*)&Qs[r][d] = *(const u16x8*)&Q[g];
        *(u16x8*)&Ks[r][d] = *(const u16x8*)&K[g];
        vv[p] = *(const u16x8*)&V[g];
    }
    __syncthreads();

    // ---- S = Q K^T; V scatter interleaved (ds_write ∥ MFMA) ----
    const int rb = wave * 32;
    f32x4 s[2][8] = {};
    #pragma unroll
    for (int d0 = 0; d0 < 64; d0 += 32) {
        u16x8 a[2], b[8];
        #pragma unroll
        for (int mi = 0; mi < 2; ++mi)
            a[mi] = *(const u16x8*)&Qs[rb + mi * 16 + (lane & 15)][d0 + (lane >> 4) * 8];
        #pragma unroll
        for (int ni = 0; ni < 8; ++ni)
            b[ni] = *(const u16x8*)&Ks[ni * 16 + (lane & 15)][d0 + (lane >> 4) * 8];
        #pragma unroll
        for (int mi = 0; mi < 2; ++mi)
            #pragma unroll
            for (int ni = 0; ni < 8; ++ni)
                s[mi][ni] = mfma16(a[mi], b[ni], s[mi][ni]);
    }
    // V transpose scatter (bank-heavy, overlaps the MFMA/shuffle work above
    // and below; completion enforced by the __syncthreads before PV)
    #pragma unroll
    for (int p = 0; p < 4; ++p) {
        int f = p * 2048 + t * 8;
        int r = f >> 6;
        int d = f & 63;
        #pragma unroll
        for (int j = 0; j < 8; ++j) Vst[d + j][r] = vv[p][j];
    }
    __syncthreads();   // Q/K reads + V writes done; P may overlay Q/K

    // ---- softmax per row ----
    #pragma unroll
    for (int mi = 0; mi < 2; ++mi) {
        #pragma unroll
        for (int q = 0; q < 4; ++q) {
            float m = -1e30f;
            #pragma unroll
            for (int ni = 0; ni < 8; ++ni) m = fmaxf(m, s[mi][ni][q]);
            m = fmaxf(m, __shfl_xor(m, 1));
            m = fmaxf(m, __shfl_xor(m, 2));
            m = fmaxf(m, __shfl_xor(m, 4));
            m = fmaxf(m, __shfl_xor(m, 8));
            float p[8], sum = 0.f;
            #pragma unroll
            for (int ni = 0; ni < 8; ++ni) { p[ni] = __expf(s[mi][ni][q] - m); sum += p[ni]; }
            sum += __shfl_xor(sum, 1);
            sum += __shfl_xor(sum, 2);
            sum += __shfl_xor(sum, 4);
            sum += __shfl_xor(sum, 8);
            float inv = 1.0f / sum;
            int row = rb + mi * 16 + ((lane >> 4) << 2) + q;
            #pragma unroll
            for (int ni = 0; ni < 8; ++ni)
                Ps[row][ni * 16 + (lane & 15)] = f2bf(p[ni] * inv);
        }
    }
    __syncthreads();

    // ---- O = P V ----
    f32x4 o[2][4] = {};
    #pragma unroll
    for (int v0 = 0; v0 < 128; v0 += 32) {
        u16x8 a[2], b[4];
        #pragma unroll
        for (int mi = 0; mi < 2; ++mi)
            a[mi] = *(const u16x8*)&Ps[rb + mi * 16 + (lane & 15)][v0 + (lane >> 4) * 8];
        #pragma unroll
        for (int ni = 0; ni < 4; ++ni)
            b[ni] = *(const u16x8*)&Vst[ni * 16 + (lane & 15)][v0 + (lane >> 4) * 8];
        #pragma unroll
        for (int mi = 0; mi < 2; ++mi)
            #pragma unroll
            for (int ni = 0; ni < 4; ++ni)
                o[mi][ni] = mfma16(a[mi], b[ni], o[mi][ni]);
    }

    #pragma unroll
    for (int mi = 0; mi < 2; ++mi)
        #pragma unroll
        for (int ni = 0; ni < 4; ++ni)
            #pragma unroll
            for (int q = 0; q < 4; ++q) {
                int row = rb + mi * 16 + ((lane >> 4) << 2) + q;
                int col = ni * 16 + (lane & 15);
                long g = ((long)(pos * mult + row * stride)) * 768 + head * 64 + col;
                O[g] = f2bf(o[mi][ni][q]);
            }
}

extern "C" void kernel_launch(void* const* d_in, const int* in_sizes, int n_in,
                              void* d_out, int out_size, void* d_ws, size_t ws_size,
                              hipStream_t stream) {
    const float* x  = (const float*)d_in[0];
    const float* Wq = (const float*)d_in[1];
    const float* bq = (const float*)d_in[2];
    const float* Wk = (const float*)d_in[3];
    const float* bk = (const float*)d_in[4];
    const float* Wv = (const float*)d_in[5];
    const float* bv = (const float*)d_in[6];
    const float* Wo = (const float*)d_in[7];
    const float* bo = (const float*)d_in[8];
    float* out = (float*)d_out;

    const size_t MS = (size_t)16384 * 768;
    const size_t WS = (size_t)768 * 768;
    unsigned short* xb   = (unsigned short*)d_ws;   // later reused as O1
    unsigned short* Qb   = xb + MS;
    unsigned short* Kb   = Qb + MS;
    unsigned short* Vb   = Kb + MS;                 // later reused as O2
    unsigned short* Wqkv = Vb + MS;
    unsigned short* Wob  = Wqkv + 3 * WS;

    cvt_f32_bf16<<<2048, 256, 0, stream>>>(x, xb, (int)MS);
    cvt4_f32_bf16<<<2304, 256, 0, stream>>>(Wq, Wk, Wv, Wo, Wqkv, (int)WS);

    // QKV projection: M=16384, N=2304 (Q|K|V), K=768. 128x18 = 2304 blocks.
    qkv_gemm<<<2304, 256, 0, stream>>>(
        xb, Wqkv, bq, bk, bv, Qb, Kb, Vb, 768, 18);

    // width attention. O1 -> xb
    attn128<<<dim3(128, 12), 256, 0, stream>>>(Qb, Kb, Vb, xb, 128, 1);
    // height attention: V-input = O1 (xb). O2 -> Vb
    attn128<<<dim3(128, 12), 256, 0, stream>>>(Qb, Kb, xb, Vb, 1, 128);

    // output projection: M=16384, N=768, K=768, fp32 out. 128x6 = 768 blocks.
    oproj_gemm<<<768, 256, 0, stream>>>(
        Vb, Wob, bo, bo, bo, out, out, out, 768, 6);
}

// Round 12
// 167.741 us; speedup vs baseline: 1.6812x; 1.6812x over previous
//
#include <hip/hip_runtime.h>

typedef __attribute__((ext_vector_type(4))) float f32x4;
typedef __attribute__((ext_vector_type(8))) unsigned short u16x8;
typedef __attribute__((ext_vector_type(8))) __bf16 bf16x8;

typedef __attribute__((address_space(3))) unsigned lds_u32;
typedef const __attribute__((address_space(1))) unsigned glb_u32;

__device__ __forceinline__ unsigned short f2bf(float f) {
    union { float f; unsigned u; } v; v.f = f;
    unsigned r = v.u + 0x7fffu + ((v.u >> 16) & 1u);
    return (unsigned short)(r >> 16);
}

__device__ __forceinline__ f32x4 mfma16(u16x8 a, u16x8 b, f32x4 c) {
    return __builtin_amdgcn_mfma_f32_16x16x32_bf16(
        __builtin_bit_cast(bf16x8, a), __builtin_bit_cast(bf16x8, b), c, 0, 0, 0);
}

__device__ __forceinline__ void gload16(const unsigned short* g, unsigned short* l) {
    __builtin_amdgcn_global_load_lds((glb_u32*)g, (lds_u32*)l, 16, 0, 0);
}

#define BARM() asm volatile("s_barrier" ::: "memory")
#define WAITVM0() asm volatile("s_waitcnt vmcnt(0)" ::: "memory")

// ---------------- fp32 -> bf16 conversions ----------------
__global__ void cvt_f32_bf16(const float* __restrict__ src,
                             unsigned short* __restrict__ dst, int n) {
    int stride = gridDim.x * blockDim.x * 4;
    for (int i = (blockIdx.x * blockDim.x + threadIdx.x) * 4; i < n; i += stride) {
        float4 f = *reinterpret_cast<const float4*>(src + i);
        ushort4 o;
        o.x = f2bf(f.x); o.y = f2bf(f.y); o.z = f2bf(f.z); o.w = f2bf(f.w);
        *reinterpret_cast<ushort4*>(dst + i) = o;
    }
}

__global__ void cvt4_f32_bf16(const float* __restrict__ s0, const float* __restrict__ s1,
                              const float* __restrict__ s2, const float* __restrict__ s3,
                              unsigned short* __restrict__ dst, int per) {
    int total = per * 4;
    int stride = gridDim.x * blockDim.x * 4;
    for (int i = (blockIdx.x * blockDim.x + threadIdx.x) * 4; i < total; i += stride) {
        int w = i / per, off = i - w * per;
        const float* s = w == 0 ? s0 : w == 1 ? s1 : w == 2 ? s2 : s3;
        float4 f = *reinterpret_cast<const float4*>(s + off);
        ushort4 o;
        o.x = f2bf(f.x); o.y = f2bf(f.y); o.z = f2bf(f.z); o.w = f2bf(f.w);
        *reinterpret_cast<ushort4*>(dst + i) = o;
    }
}

// ---------- 128x128 / BK=64 / single-buffer GEMM (R10 proven config) ----------
// C = A * B^T + bias. A: M x K bf16 row-major. B: N x K bf16 row-major. K%64==0.
// 256 threads = 4 waves (2x2, 64x64 per wave). LDS 32 KB single buffer.
// __launch_bounds__(256,4): allocator targets 4 waves/EU (VGPR<=128, actual 64,
// NO spill). Hardware residency is LDS-limited at ~5 blocks/CU regardless --
// R11's (256,5) only capped registers -> scratch spill -> 5x WRITE_SIZE. Reverted.
// Swizzle: 16B-slot cb of row r at cb ^ ((r&7)<<4); staged via pre-swizzled
// source col cel = ((t&7)^((t>>3)&7))*8 (involution; reads conflict-free).
// Sync (m97): STAGE(kt); vmcnt(0); barrier; reads+MFMA; barrier.
template<bool OUTF32>
__device__ __forceinline__ void gemm_core(
    const unsigned short* __restrict__ A,
    const unsigned short* __restrict__ B,
    const float* __restrict__ b0, const float* __restrict__ b1, const float* __restrict__ b2,
    void* __restrict__ C0, void* __restrict__ C1, void* __restrict__ C2,
    int K, int NBY)
{
    __shared__ char lds[32768];
    const int t = threadIdx.x, lane = t & 63, wave = t >> 6;
    const int wm = wave >> 1, wn = wave & 1;     // 2x2 wave grid, 64x64 each

    // XCD-aware bijective swizzle (nwg % 8 == 0 by launch)
    const int nwg = gridDim.x;
    const int bid = blockIdx.x;
    const int swzb = (bid & 7) * (nwg >> 3) + (bid >> 3);
    const long m0 = (long)(swzb / NBY) * 128;
    const long n0 = (long)(swzb % NBY) * 128;

    const int NT = K >> 6;                       // K-tiles of 64

    const int rloc = t >> 3;                                 // 0..31
    const int cel  = ((t & 7) ^ ((t >> 3) & 7)) << 3;        // src col element
    const unsigned short* Ab = A + (m0 + rloc) * (long)K + cel;
    const unsigned short* Bb = B + (n0 + rloc) * (long)K + cel;

    auto STAGE = [&](int kt) {
        char* da = lds + (wave << 10);
        char* db = lds + 16384 + (wave << 10);
        const unsigned short* sa = Ab + kt * 64;
        const unsigned short* sb = Bb + kt * 64;
        #pragma unroll
        for (int j = 0; j < 4; ++j) {
            gload16(sa + (long)(j * 32) * K, (unsigned short*)(da + j * 4096));
            gload16(sb + (long)(j * 32) * K, (unsigned short*)(db + j * 4096));
        }
    };

    f32x4 acc[4][4] = {};
    u16x8 af[4][2], bfr[4][2];

    auto LD = [&]() {
        const char* bufA = lds;
        const char* bufB = lds + 16384;
        #pragma unroll
        for (int f = 0; f < 4; ++f)
            #pragma unroll
            for (int kk = 0; kk < 2; ++kk) {
                int ra = wm * 64 + f * 16 + (lane & 15);
                int rb = wn * 64 + f * 16 + (lane & 15);
                int cb = kk * 64 + (lane >> 4) * 16;
                af[f][kk]  = *(const u16x8*)(bufA + ra * 128 + (cb ^ ((ra & 7) << 4)));
                bfr[f][kk] = *(const u16x8*)(bufB + rb * 128 + (cb ^ ((rb & 7) << 4)));
            }
    };

    for (int kt = 0; kt < NT; ++kt) {
        STAGE(kt);
        WAITVM0();
        BARM();                       // buffer ready for all waves
        LD();                         // 16 x ds_read_b128
        #pragma unroll
        for (int kk = 0; kk < 2; ++kk)
            #pragma unroll
            for (int mi = 0; mi < 4; ++mi)
                #pragma unroll
                for (int nf = 0; nf < 4; ++nf)
                    acc[mi][nf] = mfma16(af[mi][kk], bfr[nf][kk], acc[mi][nf]);
        BARM();                       // all reads done -> next STAGE safe
    }

    // ---- epilogue: C/D layout col=lane&15, row=(lane>>4)*4+reg ----
    #pragma unroll
    for (int mi = 0; mi < 4; ++mi)
        #pragma unroll
        for (int nf = 0; nf < 4; ++nf) {
            int coln = (int)n0 + wn * 64 + nf * 16 + (lane & 15);
            int which = coln / 768;
            int nl = coln - which * 768;
            const float* bs = which == 0 ? b0 : (which == 1 ? b1 : b2);
            void* Cp       = which == 0 ? C0 : (which == 1 ? C1 : C2);
            float bias = bs[nl];
            #pragma unroll
            for (int q = 0; q < 4; ++q) {
                long row = m0 + wm * 64 + mi * 16 + ((lane >> 4) << 2) + q;
                float val = acc[mi][nf][q] + bias;
                if (OUTF32) ((float*)Cp)[row * 768 + nl] = val;
                else ((unsigned short*)Cp)[row * 768 + nl] = f2bf(val);
            }
        }
}

__global__ __launch_bounds__(256, 4) void qkv_gemm(
    const unsigned short* __restrict__ A, const unsigned short* __restrict__ B,
    const float* b0, const float* b1, const float* b2,
    void* C0, void* C1, void* C2, int K, int NBY)
{
    gemm_core<false>(A, B, b0, b1, b2, C0, C1, C2, K, NBY);
}

__global__ __launch_bounds__(256, 4) void oproj_gemm(
    const unsigned short* __restrict__ A, const unsigned short* __restrict__ B,
    const float* b0, const float* b1, const float* b2,
    void* C0, void* C1, void* C2, int K, int NBY)
{
    gemm_core<true>(A, B, b0, b1, b2, C0, C1, C2, K, NBY);
}

// ---------------- axial attention, seq len 128, head_dim 64 ----------------
// V loaded to registers during staging; the (bank-conflicted) transpose
// scatter into Vst is deferred into the QK^T phase so its ds_write traffic
// overlaps the MFMA pipe instead of sitting serially before the first barrier.
__global__ __launch_bounds__(256, 3) void attn128(
    const unsigned short* __restrict__ Q,
    const unsigned short* __restrict__ K,
    const unsigned short* __restrict__ V,
    unsigned short* __restrict__ O,
    int mult, int stride)
{
    __shared__ unsigned short QK[2][128][72];
    __shared__ unsigned short Vst[64][136];
    unsigned short (*Qs)[72] = QK[0];
    unsigned short (*Ks)[72] = QK[1];
    unsigned short (*Ps)[136] = (unsigned short (*)[136])&QK[0][0][0];

    const int pos = blockIdx.x, head = blockIdx.y;
    const int t = threadIdx.x, wave = t >> 6, lane = t & 63;

    // ---- stage Q,K to LDS; V only to registers ----
    u16x8 vv[4];
    #pragma unroll
    for (int p = 0; p < 4; ++p) {
        int f = p * 2048 + t * 8;
        int r = f >> 6;
        int d = f & 63;
        long g = ((long)(pos * mult + r * stride)) * 768 + head * 64 + d;
        *(u16x8*)&Qs[r][d] = *(const u16x8*)&Q[g];
        *(u16x8*)&Ks[r][d] = *(const u16x8*)&K[g];
        vv[p] = *(const u16x8*)&V[g];
    }
    __syncthreads();

    // ---- S = Q K^T; V scatter interleaved (ds_write ∥ MFMA) ----
    const int rb = wave * 32;
    f32x4 s[2][8] = {};
    #pragma unroll
    for (int d0 = 0; d0 < 64; d0 += 32) {
        u16x8 a[2], b[8];
        #pragma unroll
        for (int mi = 0; mi < 2; ++mi)
            a[mi] = *(const u16x8*)&Qs[rb + mi * 16 + (lane & 15)][d0 + (lane >> 4) * 8];
        #pragma unroll
        for (int ni = 0; ni < 8; ++ni)
            b[ni] = *(const u16x8*)&Ks[ni * 16 + (lane & 15)][d0 + (lane >> 4) * 8];
        #pragma unroll
        for (int mi = 0; mi < 2; ++mi)
            #pragma unroll
            for (int ni = 0; ni < 8; ++ni)
                s[mi][ni] = mfma16(a[mi], b[ni], s[mi][ni]);
    }
    // V transpose scatter (bank-heavy, overlaps MFMA above; completion
    // enforced by the __syncthreads before PV)
    #pragma unroll
    for (int p = 0; p < 4; ++p) {
        int f = p * 2048 + t * 8;
        int r = f >> 6;
        int d = f & 63;
        #pragma unroll
        for (int j = 0; j < 8; ++j) Vst[d + j][r] = vv[p][j];
    }
    __syncthreads();   // Q/K reads + V writes done; P may overlay Q/K

    // ---- softmax per row ----
    #pragma unroll
    for (int mi = 0; mi < 2; ++mi) {
        #pragma unroll
        for (int q = 0; q < 4; ++q) {
            float m = -1e30f;
            #pragma unroll
            for (int ni = 0; ni < 8; ++ni) m = fmaxf(m, s[mi][ni][q]);
            m = fmaxf(m, __shfl_xor(m, 1));
            m = fmaxf(m, __shfl_xor(m, 2));
            m = fmaxf(m, __shfl_xor(m, 4));
            m = fmaxf(m, __shfl_xor(m, 8));
            float p[8], sum = 0.f;
            #pragma unroll
            for (int ni = 0; ni < 8; ++ni) { p[ni] = __expf(s[mi][ni][q] - m); sum += p[ni]; }
            sum += __shfl_xor(sum, 1);
            sum += __shfl_xor(sum, 2);
            sum += __shfl_xor(sum, 4);
            sum += __shfl_xor(sum, 8);
            float inv = 1.0f / sum;
            int row = rb + mi * 16 + ((lane >> 4) << 2) + q;
            #pragma unroll
            for (int ni = 0; ni < 8; ++ni)
                Ps[row][ni * 16 + (lane & 15)] = f2bf(p[ni] * inv);
        }
    }
    __syncthreads();

    // ---- O = P V ----
    f32x4 o[2][4] = {};
    #pragma unroll
    for (int v0 = 0; v0 < 128; v0 += 32) {
        u16x8 a[2], b[4];
        #pragma unroll
        for (int mi = 0; mi < 2; ++mi)
            a[mi] = *(const u16x8*)&Ps[rb + mi * 16 + (lane & 15)][v0 + (lane >> 4) * 8];
        #pragma unroll
        for (int ni = 0; ni < 4; ++ni)
            b[ni] = *(const u16x8*)&Vst[ni * 16 + (lane & 15)][v0 + (lane >> 4) * 8];
        #pragma unroll
        for (int mi = 0; mi < 2; ++mi)
            #pragma unroll
            for (int ni = 0; ni < 4; ++ni)
                o[mi][ni] = mfma16(a[mi], b[ni], o[mi][ni]);
    }

    #pragma unroll
    for (int mi = 0; mi < 2; ++mi)
        #pragma unroll
        for (int ni = 0; ni < 4; ++ni)
            #pragma unroll
            for (int q = 0; q < 4; ++q) {
                int row = rb + mi * 16 + ((lane >> 4) << 2) + q;
                int col = ni * 16 + (lane & 15);
                long g = ((long)(pos * mult + row * stride)) * 768 + head * 64 + col;
                O[g] = f2bf(o[mi][ni][q]);
            }
}

extern "C" void kernel_launch(void* const* d_in, const int* in_sizes, int n_in,
                              void* d_out, int out_size, void* d_ws, size_t ws_size,
                              hipStream_t stream) {
    const float* x  = (const float*)d_in[0];
    const float* Wq = (const float*)d_in[1];
    const float* bq = (const float*)d_in[2];
    const float* Wk = (const float*)d_in[3];
    const float* bk = (const float*)d_in[4];
    const float* Wv = (const float*)d_in[5];
    const float* bv = (const float*)d_in[6];
    const float* Wo = (const float*)d_in[7];
    const float* bo = (const float*)d_in[8];
    float* out = (float*)d_out;

    const size_t MS = (size_t)16384 * 768;
    const size_t WS = (size_t)768 * 768;
    unsigned short* xb   = (unsigned short*)d_ws;   // later reused as O1
    unsigned short* Qb   = xb + MS;
    unsigned short* Kb   = Qb + MS;
    unsigned short* Vb   = Kb + MS;                 // later reused as O2
    unsigned short* Wqkv = Vb + MS;
    unsigned short* Wob  = Wqkv + 3 * WS;

    cvt_f32_bf16<<<2048, 256, 0, stream>>>(x, xb, (int)MS);
    cvt4_f32_bf16<<<2304, 256, 0, stream>>>(Wq, Wk, Wv, Wo, Wqkv, (int)WS);

    // QKV projection: M=16384, N=2304 (Q|K|V), K=768. 128x18 = 2304 blocks.
    qkv_gemm<<<2304, 256, 0, stream>>>(
        xb, Wqkv, bq, bk, bv, Qb, Kb, Vb, 768, 18);

    // width attention. O1 -> xb
    attn128<<<dim3(128, 12), 256, 0, stream>>>(Qb, Kb, Vb, xb, 128, 1);
    // height attention: V-input = O1 (xb). O2 -> Vb
    attn128<<<dim3(128, 12), 256, 0, stream>>>(Qb, Kb, xb, Vb, 1, 128);

    // output projection: M=16384, N=768, K=768, fp32 out. 128x6 = 768 blocks.
    oproj_gemm<<<768, 256, 0, stream>>>(
        Vb, Wob, bo, bo, bo, out, out, out, 768, 6);
}

// Round 13
// 167.611 us; speedup vs baseline: 1.6825x; 1.0008x over previous
//
#include <hip/hip_runtime.h>

typedef __attribute__((ext_vector_type(4))) float f32x4;
typedef __attribute__((ext_vector_type(8))) unsigned short u16x8;
typedef __attribute__((ext_vector_type(8))) __bf16 bf16x8;

typedef __attribute__((address_space(3))) unsigned lds_u32;
typedef const __attribute__((address_space(1))) unsigned glb_u32;

__device__ __forceinline__ unsigned short f2bf(float f) {
    union { float f; unsigned u; } v; v.f = f;
    unsigned r = v.u + 0x7fffu + ((v.u >> 16) & 1u);
    return (unsigned short)(r >> 16);
}

__device__ __forceinline__ f32x4 mfma16(u16x8 a, u16x8 b, f32x4 c) {
    return __builtin_amdgcn_mfma_f32_16x16x32_bf16(
        __builtin_bit_cast(bf16x8, a), __builtin_bit_cast(bf16x8, b), c, 0, 0, 0);
}

__device__ __forceinline__ void gload16(const unsigned short* g, unsigned short* l) {
    __builtin_amdgcn_global_load_lds((glb_u32*)g, (lds_u32*)l, 16, 0, 0);
}

#define BARM() asm volatile("s_barrier" ::: "memory")
#define WAITVM0() asm volatile("s_waitcnt vmcnt(0)" ::: "memory")

// ------------- fused fp32 -> bf16 conversion (x + 4 weight mats) -------------
__global__ void cvt_all(const float* __restrict__ x,
                        const float* __restrict__ w0, const float* __restrict__ w1,
                        const float* __restrict__ w2, const float* __restrict__ w3,
                        unsigned short* __restrict__ xb,
                        unsigned short* __restrict__ wb,
                        int nx, int perw) {
    int total = nx + perw * 4;
    int stride = gridDim.x * blockDim.x * 4;
    for (int i = (blockIdx.x * blockDim.x + threadIdx.x) * 4; i < total; i += stride) {
        const float* s;
        unsigned short* d;
        if (i < nx) { s = x + i; d = xb + i; }
        else {
            int j = i - nx;
            int w = j / perw, off = j - w * perw;
            s = (w == 0 ? w0 : w == 1 ? w1 : w == 2 ? w2 : w3) + off;
            d = wb + j;
        }
        float4 f = *reinterpret_cast<const float4*>(s);
        ushort4 o;
        o.x = f2bf(f.x); o.y = f2bf(f.y); o.z = f2bf(f.z); o.w = f2bf(f.w);
        *reinterpret_cast<ushort4*>(d) = o;
    }
}

// ---------- 128x128 / BK=64 / single-buffer GEMM (R10/R12 proven) ----------
// C = A * B^T + bias. A: M x K bf16 row-major. B: N x K bf16 row-major. K%64==0.
// 256 threads = 4 waves (2x2, 64x64 per wave). LDS 32 KB single buffer ->
// LDS-limited ~5 blocks/CU; launch_bounds(256,4) keeps VGPR=64, no spill
// (R11 lesson: (256,5) capped regs -> scratch spill -> 5x WRITE_SIZE).
// Swizzle: 16B-slot cb of row r at cb ^ ((r&7)<<4); staged via pre-swizzled
// source col cel = ((t&7)^((t>>3)&7))*8 (involution; reads conflict-free).
// Sync (m97): STAGE(kt); vmcnt(0); barrier; reads+MFMA; barrier.
template<bool OUTF32>
__device__ __forceinline__ void gemm_core(
    const unsigned short* __restrict__ A,
    const unsigned short* __restrict__ B,
    const float* __restrict__ b0, const float* __restrict__ b1, const float* __restrict__ b2,
    void* __restrict__ C0, void* __restrict__ C1, void* __restrict__ C2,
    int K, int NBY)
{
    __shared__ char lds[32768];
    const int t = threadIdx.x, lane = t & 63, wave = t >> 6;
    const int wm = wave >> 1, wn = wave & 1;     // 2x2 wave grid, 64x64 each

    // XCD-aware bijective swizzle (nwg % 8 == 0 by launch)
    const int nwg = gridDim.x;
    const int bid = blockIdx.x;
    const int swzb = (bid & 7) * (nwg >> 3) + (bid >> 3);
    const long m0 = (long)(swzb / NBY) * 128;
    const long n0 = (long)(swzb % NBY) * 128;

    const int NT = K >> 6;                       // K-tiles of 64

    const int rloc = t >> 3;                                 // 0..31
    const int cel  = ((t & 7) ^ ((t >> 3) & 7)) << 3;        // src col element
    const unsigned short* Ab = A + (m0 + rloc) * (long)K + cel;
    const unsigned short* Bb = B + (n0 + rloc) * (long)K + cel;

    auto STAGE = [&](int kt) {
        char* da = lds + (wave << 10);
        char* db = lds + 16384 + (wave << 10);
        const unsigned short* sa = Ab + kt * 64;
        const unsigned short* sb = Bb + kt * 64;
        #pragma unroll
        for (int j = 0; j < 4; ++j) {
            gload16(sa + (long)(j * 32) * K, (unsigned short*)(da + j * 4096));
            gload16(sb + (long)(j * 32) * K, (unsigned short*)(db + j * 4096));
        }
    };

    f32x4 acc[4][4] = {};
    u16x8 af[4][2], bfr[4][2];

    auto LD = [&]() {
        const char* bufA = lds;
        const char* bufB = lds + 16384;
        #pragma unroll
        for (int f = 0; f < 4; ++f)
            #pragma unroll
            for (int kk = 0; kk < 2; ++kk) {
                int ra = wm * 64 + f * 16 + (lane & 15);
                int rb = wn * 64 + f * 16 + (lane & 15);
                int cb = kk * 64 + (lane >> 4) * 16;
                af[f][kk]  = *(const u16x8*)(bufA + ra * 128 + (cb ^ ((ra & 7) << 4)));
                bfr[f][kk] = *(const u16x8*)(bufB + rb * 128 + (cb ^ ((rb & 7) << 4)));
            }
    };

    for (int kt = 0; kt < NT; ++kt) {
        STAGE(kt);
        WAITVM0();
        BARM();                       // buffer ready for all waves
        LD();                         // 16 x ds_read_b128
        #pragma unroll
        for (int kk = 0; kk < 2; ++kk)
            #pragma unroll
            for (int mi = 0; mi < 4; ++mi)
                #pragma unroll
                for (int nf = 0; nf < 4; ++nf)
                    acc[mi][nf] = mfma16(af[mi][kk], bfr[nf][kk], acc[mi][nf]);
        BARM();                       // all reads done -> next STAGE safe
    }

    // ---- epilogue: C/D layout col=lane&15, row=(lane>>4)*4+reg ----
    #pragma unroll
    for (int mi = 0; mi < 4; ++mi)
        #pragma unroll
        for (int nf = 0; nf < 4; ++nf) {
            int coln = (int)n0 + wn * 64 + nf * 16 + (lane & 15);
            int which = coln / 768;
            int nl = coln - which * 768;
            const float* bs = which == 0 ? b0 : (which == 1 ? b1 : b2);
            void* Cp       = which == 0 ? C0 : (which == 1 ? C1 : C2);
            float bias = bs[nl];
            #pragma unroll
            for (int q = 0; q < 4; ++q) {
                long row = m0 + wm * 64 + mi * 16 + ((lane >> 4) << 2) + q;
                float val = acc[mi][nf][q] + bias;
                if (OUTF32) ((float*)Cp)[row * 768 + nl] = val;
                else ((unsigned short*)Cp)[row * 768 + nl] = f2bf(val);
            }
        }
}

__global__ __launch_bounds__(256, 4) void qkv_gemm(
    const unsigned short* __restrict__ A, const unsigned short* __restrict__ B,
    const float* b0, const float* b1, const float* b2,
    void* C0, void* C1, void* C2, int K, int NBY)
{
    gemm_core<false>(A, B, b0, b1, b2, C0, C1, C2, K, NBY);
}

__global__ __launch_bounds__(256, 4) void oproj_gemm(
    const unsigned short* __restrict__ A, const unsigned short* __restrict__ B,
    const float* b0, const float* b1, const float* b2,
    void* C0, void* C1, void* C2, int K, int NBY)
{
    gemm_core<true>(A, B, b0, b1, b2, C0, C1, C2, K, NBY);
}

// ---------------- axial attention, seq len 128, head_dim 64 ----------------
// Q/K tiles are 16 KB -> L2-resident; fragments are read DIRECTLY from global
// (Common-mistake #7: don't LDS-stage what L2 already serves). Only V (needs
// transpose) and P (layout cross-over) touch LDS. One barrier total.
__global__ __launch_bounds__(256, 3) void attn128(
    const unsigned short* __restrict__ Q,
    const unsigned short* __restrict__ K,
    const unsigned short* __restrict__ V,
    unsigned short* __restrict__ O,
    int mult, int stride)
{
    __shared__ unsigned short Vst[64][136];   // V transposed: Vst[d][v]
    __shared__ unsigned short Ps[128][136];

    const int pos = blockIdx.x, head = blockIdx.y;
    const int t = threadIdx.x, wave = t >> 6, lane = t & 63;
    const long hbase = (long)head * 64;

    // ---- V: coalesced load to regs (scatter deferred past QK^T) ----
    u16x8 vv[4];
    #pragma unroll
    for (int p = 0; p < 4; ++p) {
        int f = p * 2048 + t * 8;
        int r = f >> 6;
        int d = f & 63;
        vv[p] = *(const u16x8*)&V[((long)(pos * mult + r * stride)) * 768 + hbase + d];
    }

    // ---- S = Q K^T, fragments straight from global/L2 ----
    const int rb = wave * 32;
    const int c16 = lane & 15;             // fragment row-within-16
    const int dof = (lane >> 4) * 8;       // fragment k-offset
    f32x4 s[2][8] = {};
    #pragma unroll
    for (int d0 = 0; d0 < 64; d0 += 32) {
        u16x8 a[2], b[8];
        #pragma unroll
        for (int mi = 0; mi < 2; ++mi)
            a[mi] = *(const u16x8*)&Q[((long)(pos * mult + (rb + mi * 16 + c16) * stride)) * 768
                                      + hbase + d0 + dof];
        #pragma unroll
        for (int ni = 0; ni < 8; ++ni)
            b[ni] = *(const u16x8*)&K[((long)(pos * mult + (ni * 16 + c16) * stride)) * 768
                                      + hbase + d0 + dof];
        #pragma unroll
        for (int mi = 0; mi < 2; ++mi)
            #pragma unroll
            for (int ni = 0; ni < 8; ++ni)
                s[mi][ni] = mfma16(a[mi], b[ni], s[mi][ni]);
    }

    // ---- V transpose scatter (overlaps MFMA tail; ordered by the barrier) ----
    #pragma unroll
    for (int p = 0; p < 4; ++p) {
        int f = p * 2048 + t * 8;
        int r = f >> 6;
        int d = f & 63;
        #pragma unroll
        for (int j = 0; j < 8; ++j) Vst[d + j][r] = vv[p][j];
    }

    // ---- softmax per row -> Ps ----
    #pragma unroll
    for (int mi = 0; mi < 2; ++mi) {
        #pragma unroll
        for (int q = 0; q < 4; ++q) {
            float m = -1e30f;
            #pragma unroll
            for (int ni = 0; ni < 8; ++ni) m = fmaxf(m, s[mi][ni][q]);
            m = fmaxf(m, __shfl_xor(m, 1));
            m = fmaxf(m, __shfl_xor(m, 2));
            m = fmaxf(m, __shfl_xor(m, 4));
            m = fmaxf(m, __shfl_xor(m, 8));
            float p[8], sum = 0.f;
            #pragma unroll
            for (int ni = 0; ni < 8; ++ni) { p[ni] = __expf(s[mi][ni][q] - m); sum += p[ni]; }
            sum += __shfl_xor(sum, 1);
            sum += __shfl_xor(sum, 2);
            sum += __shfl_xor(sum, 4);
            sum += __shfl_xor(sum, 8);
            float inv = 1.0f / sum;
            int row = rb + mi * 16 + ((lane >> 4) << 2) + q;
            #pragma unroll
            for (int ni = 0; ni < 8; ++ni)
                Ps[row][ni * 16 + c16] = f2bf(p[ni] * inv);
        }
    }
    __syncthreads();   // Vst + Ps complete

    // ---- O = P V ----
    f32x4 o[2][4] = {};
    #pragma unroll
    for (int v0 = 0; v0 < 128; v0 += 32) {
        u16x8 a[2], b[4];
        #pragma unroll
        for (int mi = 0; mi < 2; ++mi)
            a[mi] = *(const u16x8*)&Ps[rb + mi * 16 + c16][v0 + dof];
        #pragma unroll
        for (int ni = 0; ni < 4; ++ni)
            b[ni] = *(const u16x8*)&Vst[ni * 16 + c16][v0 + dof];
        #pragma unroll
        for (int mi = 0; mi < 2; ++mi)
            #pragma unroll
            for (int ni = 0; ni < 4; ++ni)
                o[mi][ni] = mfma16(a[mi], b[ni], o[mi][ni]);
    }

    #pragma unroll
    for (int mi = 0; mi < 2; ++mi)
        #pragma unroll
        for (int ni = 0; ni < 4; ++ni)
            #pragma unroll
            for (int q = 0; q < 4; ++q) {
                int row = rb + mi * 16 + ((lane >> 4) << 2) + q;
                int col = ni * 16 + c16;
                long g = ((long)(pos * mult + row * stride)) * 768 + hbase + col;
                O[g] = f2bf(o[mi][ni][q]);
            }
}

extern "C" void kernel_launch(void* const* d_in, const int* in_sizes, int n_in,
                              void* d_out, int out_size, void* d_ws, size_t ws_size,
                              hipStream_t stream) {
    const float* x  = (const float*)d_in[0];
    const float* Wq = (const float*)d_in[1];
    const float* bq = (const float*)d_in[2];
    const float* Wk = (const float*)d_in[3];
    const float* bk = (const float*)d_in[4];
    const float* Wv = (const float*)d_in[5];
    const float* bv = (const float*)d_in[6];
    const float* Wo = (const float*)d_in[7];
    const float* bo = (const float*)d_in[8];
    float* out = (float*)d_out;

    const size_t MS = (size_t)16384 * 768;
    const size_t WS = (size_t)768 * 768;
    unsigned short* xb   = (unsigned short*)d_ws;   // later reused as O1
    unsigned short* Qb   = xb + MS;
    unsigned short* Kb   = Qb + MS;
    unsigned short* Vb   = Kb + MS;                 // later reused as O2
    unsigned short* Wqkv = Vb + MS;
    unsigned short* Wob  = Wqkv + 3 * WS;

    // fused conversion: x -> xb, {Wq,Wk,Wv,Wo} -> Wqkv..Wob (contiguous)
    cvt_all<<<2048, 256, 0, stream>>>(x, Wq, Wk, Wv, Wo, xb, Wqkv,
                                      (int)MS, (int)WS);

    // QKV projection: M=16384, N=2304 (Q|K|V), K=768. 128x18 = 2304 blocks.
    qkv_gemm<<<2304, 256, 0, stream>>>(
        xb, Wqkv, bq, bk, bv, Qb, Kb, Vb, 768, 18);

    // width attention. O1 -> xb
    attn128<<<dim3(128, 12), 256, 0, stream>>>(Qb, Kb, Vb, xb, 128, 1);
    // height attention: V-input = O1 (xb). O2 -> Vb
    attn128<<<dim3(128, 12), 256, 0, stream>>>(Qb, Kb, xb, Vb, 1, 128);

    // output projection: M=16384, N=768, K=768, fp32 out. 128x6 = 768 blocks.
    oproj_gemm<<<768, 256, 0, stream>>>(
        Vb, Wob, bo, bo, bo, out, out, out, 768, 6);
}